// Round 1
// baseline (1501.597 us; speedup 1.0000x reference)
//
#include <hip/hip_runtime.h>

typedef __attribute__((ext_vector_type(8))) short short8;
typedef __attribute__((ext_vector_type(4))) float f32x4;

#define NT 32
#define NB 64
#define NA 16
#define NF 128
#define DT 512
#define NH 8
#define NHD 64

__device__ __forceinline__ unsigned short f2b(float f) {
  union { float f; unsigned u; } c; c.f = f;
  unsigned r = c.u + 0x7fffu + ((c.u >> 16) & 1u);
  return (unsigned short)(r >> 16);
}
__device__ __forceinline__ float b2f(unsigned short u) {
  union { unsigned u; float f; } c; c.u = ((unsigned)u) << 16;
  return c.f;
}

// ---------------- weight cast: f32 -> bf16, 8 elems/thread ----------------
__global__ __launch_bounds__(256) void cast_w_kernel(const float* __restrict__ src,
                                                     unsigned short* __restrict__ dst) {
  int i = (blockIdx.x * 256 + threadIdx.x) * 8;
  float4 v0 = *(const float4*)(src + i);
  float4 v1 = *(const float4*)(src + i + 4);
  uint4 o;
  o.x = f2b(v0.x) | ((unsigned)f2b(v0.y) << 16);
  o.y = f2b(v0.z) | ((unsigned)f2b(v0.w) << 16);
  o.z = f2b(v1.x) | ((unsigned)f2b(v1.y) << 16);
  o.w = f2b(v1.z) | ((unsigned)f2b(v1.w) << 16);
  *(uint4*)(dst + i) = o;
}

// ---------------- GEMM: C = A(MxK) @ B(NxK)^T + bias, K=512 ----------------
// MODE_Q : A=f32, write bf16 row-linear (Q projection)
// MODE_KV: A=f32, N=1024: cols<512 -> K store (row-linear), cols>=512 -> V store (row permuted)
// MODE_O : A=bf16 (attn), write f32 to d_out with (t,b,a)->(t,a,b) row permutation
enum { MODE_Q = 0, MODE_KV = 1, MODE_O = 2 };

template <int MODE>
__global__ __launch_bounds__(256, 2) void gemm_bt(const void* __restrict__ Ag_,
                                                  const unsigned short* __restrict__ Bg,
                                                  const float* __restrict__ bias0,
                                                  const float* __restrict__ bias1,
                                                  void* __restrict__ C0_,
                                                  void* __restrict__ C1_) {
  __shared__ unsigned short As[128][40];  // pitch 40 to break bank alignment
  __shared__ unsigned short Bs[128][40];
  const int tid = threadIdx.x;
  const int lane = tid & 63;
  const int l4 = lane & 15, lg = lane >> 4;
  const int w = tid >> 6;
  const int wm = w >> 1, wn = w & 1;
  const long rowTile = blockIdx.x;
  const int colTile = blockIdx.y;
  const int srow = tid >> 1;
  const int scol = (tid & 1) * 16;

  const f32x4 zero = {0.f, 0.f, 0.f, 0.f};
  f32x4 acc[4][4];
#pragma unroll
  for (int i = 0; i < 4; i++)
#pragma unroll
    for (int j = 0; j < 4; j++) acc[i][j] = zero;

  for (int k0 = 0; k0 < 512; k0 += 32) {
    // stage B tile (bf16, 128 rows x 32 k)
    {
      const uint4* src = (const uint4*)(Bg + (long)(colTile * 128 + srow) * 512 + k0 + scol);
      uint4 b0 = src[0], b1 = src[1];
      *(uint4*)&Bs[srow][scol] = b0;
      *(uint4*)&Bs[srow][scol + 8] = b1;
    }
    // stage A tile
    if constexpr (MODE == MODE_O) {
      const unsigned short* Ag = (const unsigned short*)Ag_;
      const uint4* src = (const uint4*)(Ag + (rowTile * 128 + srow) * 512 + k0 + scol);
      uint4 a0 = src[0], a1 = src[1];
      *(uint4*)&As[srow][scol] = a0;
      *(uint4*)&As[srow][scol + 8] = a1;
    } else {
      const float* Ag = (const float*)Ag_;
      const float4* src = (const float4*)(Ag + (rowTile * 128 + srow) * 512 + k0 + scol);
      float4 v0 = src[0], v1 = src[1], v2 = src[2], v3 = src[3];
      uint4 o0, o1;
      o0.x = f2b(v0.x) | ((unsigned)f2b(v0.y) << 16);
      o0.y = f2b(v0.z) | ((unsigned)f2b(v0.w) << 16);
      o0.z = f2b(v1.x) | ((unsigned)f2b(v1.y) << 16);
      o0.w = f2b(v1.z) | ((unsigned)f2b(v1.w) << 16);
      o1.x = f2b(v2.x) | ((unsigned)f2b(v2.y) << 16);
      o1.y = f2b(v2.z) | ((unsigned)f2b(v2.w) << 16);
      o1.z = f2b(v3.x) | ((unsigned)f2b(v3.y) << 16);
      o1.w = f2b(v3.z) | ((unsigned)f2b(v3.w) << 16);
      *(uint4*)&As[srow][scol] = o0;
      *(uint4*)&As[srow][scol + 8] = o1;
    }
    __syncthreads();
    short8 af[4], bf[4];
#pragma unroll
    for (int i = 0; i < 4; i++) af[i] = *(const short8*)&As[wm * 64 + i * 16 + l4][lg * 8];
#pragma unroll
    for (int i = 0; i < 4; i++) bf[i] = *(const short8*)&Bs[wn * 64 + i * 16 + l4][lg * 8];
#pragma unroll
    for (int i = 0; i < 4; i++)
#pragma unroll
      for (int j = 0; j < 4; j++)
        acc[i][j] = __builtin_amdgcn_mfma_f32_16x16x32_bf16(af[i], bf[j], acc[i][j], 0, 0, 0);
    __syncthreads();
  }

  const long rowBase = rowTile * 128 + wm * 64;

  if constexpr (MODE == MODE_Q) {
    unsigned short* C = (unsigned short*)C0_;
#pragma unroll
    for (int j = 0; j < 4; j++) {
      int gCol = colTile * 128 + wn * 64 + j * 16 + l4;
      float bs = bias0[gCol];
#pragma unroll
      for (int i = 0; i < 4; i++)
#pragma unroll
        for (int r = 0; r < 4; r++) {
          long gRow = rowBase + i * 16 + lg * 4 + r;
          C[gRow * 512 + gCol] = f2b(acc[i][j][r] + bs);
        }
    }
  } else if constexpr (MODE == MODE_KV) {
    if (colTile < 4) {  // K side: row-linear (reshape is a memory no-op)
      unsigned short* C = (unsigned short*)C0_;
#pragma unroll
      for (int j = 0; j < 4; j++) {
        int gCol = colTile * 128 + wn * 64 + j * 16 + l4;
        float bs = bias0[gCol];
#pragma unroll
        for (int i = 0; i < 4; i++)
#pragma unroll
          for (int r = 0; r < 4; r++) {
            long gRow = rowBase + i * 16 + lg * 4 + r;
            C[gRow * 512 + gCol] = f2b(acc[i][j][r] + bs);
          }
      }
    } else {  // V side: row permutation (fi*64+bi) -> (bi*128+fi) within each t
      unsigned short* C = (unsigned short*)C1_;
#pragma unroll
      for (int j = 0; j < 4; j++) {
        int gCol = colTile * 128 + wn * 64 + j * 16 + l4 - 512;
        float bs = bias1[gCol];
#pragma unroll
        for (int i = 0; i < 4; i++)
#pragma unroll
          for (int r = 0; r < 4; r++) {
            long gRow = rowBase + i * 16 + lg * 4 + r;
            long rr = gRow & 8191;
            long vrow = (gRow - rr) + ((rr & 63) << 7) + (rr >> 6);
            C[vrow * 512 + gCol] = f2b(acc[i][j][r] + bs);
          }
      }
    }
  } else {  // MODE_O: rows (t*64+b)*16+a -> out row (t*16+a)*64+b, f32
    float* C = (float*)C0_;
#pragma unroll
    for (int j = 0; j < 4; j++) {
      int gCol = colTile * 128 + wn * 64 + j * 16 + l4;
      float bs = bias0[gCol];
#pragma unroll
      for (int i = 0; i < 4; i++)
#pragma unroll
        for (int r = 0; r < 4; r++) {
          long gRow = rowBase + i * 16 + lg * 4 + r;
          long tt = gRow >> 10;
          long bi = (gRow >> 4) & 63;
          long ai = gRow & 15;
          long orow = ((tt * 16 + ai) << 6) + bi;
          C[orow * 512 + gCol] = acc[i][j][r] + bs;
        }
    }
  }
}

// ---------------- attention: one block per (t,b); 4 waves x 2 heads ----------------
__global__ __launch_bounds__(256, 2) void attn_kernel(const unsigned short* __restrict__ Kst,
                                                      const unsigned short* __restrict__ Vst,
                                                      const unsigned short* __restrict__ Qst,
                                                      const int* __restrict__ mask,
                                                      float* __restrict__ wout,
                                                      unsigned short* __restrict__ attn_out) {
  __shared__ float wsh[4][NF * NA];
  __shared__ int msh[NF];
  const int tid = threadIdx.x;
  const int lane = tid & 63;
  const int l4 = lane & 15, lg = lane >> 4;
  const int w = tid >> 6;
  const int tb = blockIdx.x;
  const int b = tb & 63;
  if (tid < NF) msh[tid] = mask[b * NF + tid];
  __syncthreads();

  // rows for this (t,b): K/V rows tb*128 .. tb*128+127 (both contiguous by construction)
  const unsigned short* Kbase = Kst + (long)tb * NF * DT;
  const unsigned short* Vbase = Vst + (long)tb * NF * DT;
  const unsigned short* Qbase = Qst + (long)tb * NA * DT;
  const f32x4 zero = {0.f, 0.f, 0.f, 0.f};

  for (int hh = 0; hh < 2; hh++) {
    const int h = w * 2 + hh;
    const int co = h * 64;
    // ---- logits (f x a) = K_h (128x64) @ Q_h^T, via 16x16x32 MFMA ----
    f32x4 acc[8];
#pragma unroll
    for (int i = 0; i < 8; i++) acc[i] = zero;
#pragma unroll
    for (int ks = 0; ks < 2; ks++) {
      short8 qf = *(const short8*)(Qbase + (long)l4 * DT + co + ks * 32 + lg * 8);
#pragma unroll
      for (int m0 = 0; m0 < 8; m0++) {
        short8 kf = *(const short8*)(Kbase + (long)(m0 * 16 + l4) * DT + co + ks * 32 + lg * 8);
        acc[m0] = __builtin_amdgcn_mfma_f32_16x16x32_bf16(kf, qf, acc[m0], 0, 0, 0);
      }
    }
    // lane holds logits[f = m0*16+lg*4+r][a = l4]
    float lv[8][4];
    float mx = -3.0e38f;
#pragma unroll
    for (int m0 = 0; m0 < 8; m0++)
#pragma unroll
      for (int r = 0; r < 4; r++) {
        int f = m0 * 16 + lg * 4 + r;
        float v = acc[m0][r] * 0.125f;
        if (msh[f] == 0) v = -1.0e9f;
        lv[m0][r] = v;
        mx = fmaxf(mx, v);
      }
    mx = fmaxf(mx, __shfl_xor(mx, 16, 64));
    mx = fmaxf(mx, __shfl_xor(mx, 32, 64));
    float s = 0.f;
#pragma unroll
    for (int m0 = 0; m0 < 8; m0++)
#pragma unroll
      for (int r = 0; r < 4; r++) {
        float p = __expf(lv[m0][r] - mx);
        lv[m0][r] = p;
        s += p;
      }
    s += __shfl_xor(s, 16, 64);
    s += __shfl_xor(s, 32, 64);
    float inv = 1.0f / s;
    // write weights to d_out (f32) and LDS for PV
    float* wrow = wout + ((long)tb * NH + h) * (NF * NA);
#pragma unroll
    for (int m0 = 0; m0 < 8; m0++)
#pragma unroll
      for (int r = 0; r < 4; r++) {
        int f = m0 * 16 + lg * 4 + r;
        float wv = lv[m0][r] * inv;
        wsh[w][f * 16 + l4] = wv;
        wrow[f * 16 + l4] = wv;
      }
    // ---- PV (VALU): lane = hd, accumulate over f, all 16 a's ----
    float pv[16];
#pragma unroll
    for (int a = 0; a < 16; a++) pv[a] = 0.f;
#pragma unroll 4
    for (int f = 0; f < NF; f++) {
      float vv = b2f(Vbase[(long)f * DT + co + lane]);
      const float4* wp = (const float4*)&wsh[w][f * 16];
      float4 w0 = wp[0], w1 = wp[1], w2 = wp[2], w3 = wp[3];
      pv[0] += vv * w0.x;  pv[1] += vv * w0.y;  pv[2] += vv * w0.z;  pv[3] += vv * w0.w;
      pv[4] += vv * w1.x;  pv[5] += vv * w1.y;  pv[6] += vv * w1.z;  pv[7] += vv * w1.w;
      pv[8] += vv * w2.x;  pv[9] += vv * w2.y;  pv[10] += vv * w2.z; pv[11] += vv * w2.w;
      pv[12] += vv * w3.x; pv[13] += vv * w3.y; pv[14] += vv * w3.z; pv[15] += vv * w3.w;
    }
#pragma unroll
    for (int a = 0; a < 16; a++)
      attn_out[((long)tb * NA + a) * DT + co + lane] = f2b(pv[a]);
  }
}

extern "C" void kernel_launch(void* const* d_in, const int* in_sizes, int n_in,
                              void* d_out, int out_size, void* d_ws, size_t ws_size,
                              hipStream_t stream) {
  const float* q_embeds = (const float*)d_in[0];
  const float* ctx = (const float*)d_in[1];
  const int* mask = (const int*)d_in[2];
  const float* Wq = (const float*)d_in[3];
  const float* bq = (const float*)d_in[4];
  const float* Wk = (const float*)d_in[5];
  const float* bk = (const float*)d_in[6];
  const float* Wv = (const float*)d_in[7];
  const float* bv = (const float*)d_in[8];
  const float* Wo = (const float*)d_in[9];
  const float* bo = (const float*)d_in[10];

  float* out0 = (float*)d_out;                       // (t,a,b,d) f32
  float* wout = out0 + (long)NT * NA * NB * DT;      // (t,b,H,f,a) f32

  // workspace layout (bf16 as ushort)
  const long W_ELEMS = 4L * 512 * 512;        // 4 weight matrices
  const long MQ = (long)NT * NB * NA;         // 32768
  const long MKV = (long)NT * NF * NB;        // 262144
  unsigned short* Wb = (unsigned short*)d_ws;
  unsigned short* Qst = Wb + W_ELEMS;
  unsigned short* Kst = Qst + MQ * DT;
  unsigned short* Vst = Kst + MKV * DT;
  unsigned short* attnst = Vst + MKV * DT;
  size_t needed = (size_t)(W_ELEMS + MQ * DT + 2 * MKV * DT + MQ * DT) * 2;
  if (ws_size < needed) return;  // fail cleanly (validation will flag it)

  cast_w_kernel<<<128, 256, 0, stream>>>(Wq, Wb);
  cast_w_kernel<<<128, 256, 0, stream>>>(Wk, Wb + 512 * 512);
  cast_w_kernel<<<128, 256, 0, stream>>>(Wv, Wb + 2 * 512 * 512);
  cast_w_kernel<<<128, 256, 0, stream>>>(Wo, Wb + 3 * 512 * 512);

  gemm_bt<MODE_Q><<<dim3(MQ / 128, 4), 256, 0, stream>>>(q_embeds, Wb, bq, nullptr, Qst, nullptr);
  gemm_bt<MODE_KV><<<dim3(MKV / 128, 8), 256, 0, stream>>>(ctx, Wb + 512 * 512, bk, bv, Kst, Vst);
  attn_kernel<<<NT * NB, 256, 0, stream>>>(Kst, Vst, Qst, mask, wout, attnst);
  gemm_bt<MODE_O><<<dim3(MQ / 128, 4), 256, 0, stream>>>(attnst, Wb + 3 * 512 * 512, bo, nullptr, out0, nullptr);
}

// Round 2
// 942.627 us; speedup vs baseline: 1.5930x; 1.5930x over previous
//
#include <hip/hip_runtime.h>

typedef __attribute__((ext_vector_type(8))) short short8;
typedef __attribute__((ext_vector_type(4))) float f32x4;

#define NT 32
#define NB 64
#define NA 16
#define NF 128
#define DT 512
#define NH 8
#define NHD 64

__device__ __forceinline__ unsigned short f2b(float f) {
  union { float f; unsigned u; } c; c.f = f;
  unsigned r = c.u + 0x7fffu + ((c.u >> 16) & 1u);
  return (unsigned short)(r >> 16);
}
__device__ __forceinline__ float b2f(unsigned short u) {
  union { unsigned u; float f; } c; c.u = ((unsigned)u) << 16;
  return c.f;
}

__device__ __forceinline__ void gload16(const void* g, void* l) {
  __builtin_amdgcn_global_load_lds(
      (const __attribute__((address_space(1))) void*)g,
      (__attribute__((address_space(3))) void*)l, 16, 0, 0);
}

// ---------------- f32 -> bf16 cast, 8 elems/thread ----------------
__global__ __launch_bounds__(256) void cast_kernel(const float* __restrict__ src,
                                                   unsigned short* __restrict__ dst) {
  long i = ((long)blockIdx.x * 256 + threadIdx.x) * 8;
  float4 v0 = *(const float4*)(src + i);
  float4 v1 = *(const float4*)(src + i + 4);
  uint4 o;
  o.x = f2b(v0.x) | ((unsigned)f2b(v0.y) << 16);
  o.y = f2b(v0.z) | ((unsigned)f2b(v0.w) << 16);
  o.z = f2b(v1.x) | ((unsigned)f2b(v1.y) << 16);
  o.w = f2b(v1.z) | ((unsigned)f2b(v1.w) << 16);
  *(uint4*)(dst + i) = o;
}

// =============== m97-structure GEMM: C = A(Mx512) @ B(Nx512)^T + bias ===============
// A, B bf16 in memory; global_load_lds width-16 staging; 128x128 tile; BK=32.
// Grid flattened 1D, XCD-bijective swizzle, colTile in low CBITS bits.
enum { MODE_KV = 1, MODE_O = 2 };

template <int MODE, int CBITS>
__global__ __launch_bounds__(256) void gemm_lds(const unsigned short* __restrict__ A,
                                                const unsigned short* __restrict__ Bg,
                                                const float* __restrict__ bias0,
                                                const float* __restrict__ bias1,
                                                void* __restrict__ C0_,
                                                void* __restrict__ C1_,
                                                long row0) {
  __shared__ __align__(16) unsigned short As[128 * 32];
  __shared__ __align__(16) unsigned short Bs[128 * 32];
  const int tid = threadIdx.x;
  const int lane = tid & 63;
  const int l4 = lane & 15, lg = lane >> 4;
  const int w = tid >> 6;
  const int wm = w >> 1, wn = w & 1;

  // XCD-bijective swizzle (grid divisible by 8): xcd gets contiguous swz chunk,
  // colTile in low bits -> each XCD owns disjoint row-panels -> A fetched once.
  const int nwg = gridDim.x;
  const int bid = blockIdx.x;
  const int swz = (bid & 7) * (nwg >> 3) + (bid >> 3);
  const long rowTile = swz >> CBITS;
  const int colTile = swz & ((1 << CBITS) - 1);

  // staging: chunk = 64 lanes x 16B = 16 rows x 32 cols. wave w stages chunks w, w+4.
  const int srow = lane >> 2;           // 0..15
  const int scol = (lane & 3) * 8;      // 0,8,16,24
  const unsigned short* Ab = A + (rowTile * 128 + w * 16 + srow) * 512L + scol;
  const unsigned short* Ab2 = Ab + 64 * 512L;
  const unsigned short* Bb = Bg + ((long)colTile * 128 + w * 16 + srow) * 512L + scol;
  const unsigned short* Bb2 = Bb + 64 * 512L;
  unsigned short* lA = As + w * 512;    // wave-uniform LDS bases
  unsigned short* lA2 = As + (w + 4) * 512;
  unsigned short* lB = Bs + w * 512;
  unsigned short* lB2 = Bs + (w + 4) * 512;

  const f32x4 zero = {0.f, 0.f, 0.f, 0.f};
  f32x4 acc[4][4];
#pragma unroll
  for (int i = 0; i < 4; i++)
#pragma unroll
    for (int j = 0; j < 4; j++) acc[i][j] = zero;

  for (int k0 = 0; k0 < 512; k0 += 32) {
    gload16(Ab + k0, lA);
    gload16(Ab2 + k0, lA2);
    gload16(Bb + k0, lB);
    gload16(Bb2 + k0, lB2);
    __syncthreads();
    short8 af[4], bfr[4];
#pragma unroll
    for (int i = 0; i < 4; i++)
      af[i] = *(const short8*)(As + (wm * 64 + i * 16 + l4) * 32 + lg * 8);
#pragma unroll
    for (int j = 0; j < 4; j++)
      bfr[j] = *(const short8*)(Bs + (wn * 64 + j * 16 + l4) * 32 + lg * 8);
#pragma unroll
    for (int i = 0; i < 4; i++)
#pragma unroll
      for (int j = 0; j < 4; j++)
        acc[i][j] = __builtin_amdgcn_mfma_f32_16x16x32_bf16(af[i], bfr[j], acc[i][j], 0, 0, 0);
    __syncthreads();
  }

  const long rowBase = rowTile * 128 + wm * 64;

  if constexpr (MODE == MODE_KV) {
    if (colTile < 4) {  // K side: row-linear
      unsigned short* C = (unsigned short*)C0_;
#pragma unroll
      for (int j = 0; j < 4; j++) {
        int gCol = colTile * 128 + wn * 64 + j * 16 + l4;
        float bs = bias0[gCol];
#pragma unroll
        for (int i = 0; i < 4; i++)
#pragma unroll
          for (int r = 0; r < 4; r++) {
            long gRow = row0 + rowBase + i * 16 + lg * 4 + r;
            C[gRow * 512 + gCol] = f2b(acc[i][j][r] + bs);
          }
      }
    } else {  // V side: row permutation (fi*64+bi) -> (bi*128+fi) within each t
      unsigned short* C = (unsigned short*)C1_;
#pragma unroll
      for (int j = 0; j < 4; j++) {
        int gCol = colTile * 128 + wn * 64 + j * 16 + l4 - 512;
        float bs = bias1[gCol];
#pragma unroll
        for (int i = 0; i < 4; i++)
#pragma unroll
          for (int r = 0; r < 4; r++) {
            long gRow = row0 + rowBase + i * 16 + lg * 4 + r;
            long rr = gRow & 8191;
            long vrow = (gRow - rr) + ((rr & 63) << 7) + (rr >> 6);
            C[vrow * 512 + gCol] = f2b(acc[i][j][r] + bs);
          }
      }
    }
  } else {  // MODE_O: rows (t*64+b)*16+a -> out row (t*16+a)*64+b, f32
    float* C = (float*)C0_;
#pragma unroll
    for (int j = 0; j < 4; j++) {
      int gCol = colTile * 128 + wn * 64 + j * 16 + l4;
      float bs = bias0[gCol];
#pragma unroll
      for (int i = 0; i < 4; i++)
#pragma unroll
        for (int r = 0; r < 4; r++) {
          long gRow = rowBase + i * 16 + lg * 4 + r;
          long tt = gRow >> 10;
          long bi = (gRow >> 4) & 63;
          long ai = gRow & 15;
          long orow = ((tt * 16 + ai) << 6) + bi;
          C[orow * 512 + gCol] = acc[i][j][r] + bs;
        }
    }
  }
}

// ---------------- Q projection (A = f32, cvt in staging; small, L3-resident) ----------------
__global__ __launch_bounds__(256, 2) void gemm_q(const float* __restrict__ Ag,
                                                 const unsigned short* __restrict__ Bg,
                                                 const float* __restrict__ bias0,
                                                 unsigned short* __restrict__ C) {
  __shared__ unsigned short As[128][40];
  __shared__ unsigned short Bs[128][40];
  const int tid = threadIdx.x;
  const int lane = tid & 63;
  const int l4 = lane & 15, lg = lane >> 4;
  const int w = tid >> 6;
  const int wm = w >> 1, wn = w & 1;
  const long rowTile = blockIdx.x;
  const int colTile = blockIdx.y;
  const int srow = tid >> 1;
  const int scol = (tid & 1) * 16;

  const f32x4 zero = {0.f, 0.f, 0.f, 0.f};
  f32x4 acc[4][4];
#pragma unroll
  for (int i = 0; i < 4; i++)
#pragma unroll
    for (int j = 0; j < 4; j++) acc[i][j] = zero;

  for (int k0 = 0; k0 < 512; k0 += 32) {
    {
      const uint4* src = (const uint4*)(Bg + (long)(colTile * 128 + srow) * 512 + k0 + scol);
      uint4 b0 = src[0], b1 = src[1];
      *(uint4*)&Bs[srow][scol] = b0;
      *(uint4*)&Bs[srow][scol + 8] = b1;
    }
    {
      const float4* src = (const float4*)(Ag + (rowTile * 128 + srow) * 512 + k0 + scol);
      float4 v0 = src[0], v1 = src[1], v2 = src[2], v3 = src[3];
      uint4 o0, o1;
      o0.x = f2b(v0.x) | ((unsigned)f2b(v0.y) << 16);
      o0.y = f2b(v0.z) | ((unsigned)f2b(v0.w) << 16);
      o0.z = f2b(v1.x) | ((unsigned)f2b(v1.y) << 16);
      o0.w = f2b(v1.z) | ((unsigned)f2b(v1.w) << 16);
      o1.x = f2b(v2.x) | ((unsigned)f2b(v2.y) << 16);
      o1.y = f2b(v2.z) | ((unsigned)f2b(v2.w) << 16);
      o1.z = f2b(v3.x) | ((unsigned)f2b(v3.y) << 16);
      o1.w = f2b(v3.z) | ((unsigned)f2b(v3.w) << 16);
      *(uint4*)&As[srow][scol] = o0;
      *(uint4*)&As[srow][scol + 8] = o1;
    }
    __syncthreads();
    short8 af[4], bf[4];
#pragma unroll
    for (int i = 0; i < 4; i++) af[i] = *(const short8*)&As[wm * 64 + i * 16 + l4][lg * 8];
#pragma unroll
    for (int i = 0; i < 4; i++) bf[i] = *(const short8*)&Bs[wn * 64 + i * 16 + l4][lg * 8];
#pragma unroll
    for (int i = 0; i < 4; i++)
#pragma unroll
      for (int j = 0; j < 4; j++)
        acc[i][j] = __builtin_amdgcn_mfma_f32_16x16x32_bf16(af[i], bf[j], acc[i][j], 0, 0, 0);
    __syncthreads();
  }

  const long rowBase = rowTile * 128 + wm * 64;
#pragma unroll
  for (int j = 0; j < 4; j++) {
    int gCol = colTile * 128 + wn * 64 + j * 16 + l4;
    float bs = bias0[gCol];
#pragma unroll
    for (int i = 0; i < 4; i++)
#pragma unroll
      for (int r = 0; r < 4; r++) {
        long gRow = rowBase + i * 16 + lg * 4 + r;
        C[gRow * 512 + gCol] = f2b(acc[i][j][r] + bs);
      }
  }
}

// ---------------- attention: one block per (t,b); 4 waves x 2 heads ----------------
__global__ __launch_bounds__(256, 2) void attn_kernel(const unsigned short* __restrict__ Kst,
                                                      const unsigned short* __restrict__ Vst,
                                                      const unsigned short* __restrict__ Qst,
                                                      const int* __restrict__ mask,
                                                      float* __restrict__ wout,
                                                      unsigned short* __restrict__ attn_out) {
  __shared__ float wsh[4][NF * NA];
  __shared__ int msh[NF];
  const int tid = threadIdx.x;
  const int lane = tid & 63;
  const int l4 = lane & 15, lg = lane >> 4;
  const int w = tid >> 6;
  const int tb = blockIdx.x;
  const int b = tb & 63;
  if (tid < NF) msh[tid] = mask[b * NF + tid];
  __syncthreads();

  const unsigned short* Kbase = Kst + (long)tb * NF * DT;
  const unsigned short* Vbase = Vst + (long)tb * NF * DT;
  const unsigned short* Qbase = Qst + (long)tb * NA * DT;
  const f32x4 zero = {0.f, 0.f, 0.f, 0.f};

  for (int hh = 0; hh < 2; hh++) {
    const int h = w * 2 + hh;
    const int co = h * 64;
    f32x4 acc[8];
#pragma unroll
    for (int i = 0; i < 8; i++) acc[i] = zero;
#pragma unroll
    for (int ks = 0; ks < 2; ks++) {
      short8 qf = *(const short8*)(Qbase + (long)l4 * DT + co + ks * 32 + lg * 8);
#pragma unroll
      for (int m0 = 0; m0 < 8; m0++) {
        short8 kf = *(const short8*)(Kbase + (long)(m0 * 16 + l4) * DT + co + ks * 32 + lg * 8);
        acc[m0] = __builtin_amdgcn_mfma_f32_16x16x32_bf16(kf, qf, acc[m0], 0, 0, 0);
      }
    }
    float lv[8][4];
    float mx = -3.0e38f;
#pragma unroll
    for (int m0 = 0; m0 < 8; m0++)
#pragma unroll
      for (int r = 0; r < 4; r++) {
        int f = m0 * 16 + lg * 4 + r;
        float v = acc[m0][r] * 0.125f;
        if (msh[f] == 0) v = -1.0e9f;
        lv[m0][r] = v;
        mx = fmaxf(mx, v);
      }
    mx = fmaxf(mx, __shfl_xor(mx, 16, 64));
    mx = fmaxf(mx, __shfl_xor(mx, 32, 64));
    float s = 0.f;
#pragma unroll
    for (int m0 = 0; m0 < 8; m0++)
#pragma unroll
      for (int r = 0; r < 4; r++) {
        float p = __expf(lv[m0][r] - mx);
        lv[m0][r] = p;
        s += p;
      }
    s += __shfl_xor(s, 16, 64);
    s += __shfl_xor(s, 32, 64);
    float inv = 1.0f / s;
    float* wrow = wout + ((long)tb * NH + h) * (NF * NA);
#pragma unroll
    for (int m0 = 0; m0 < 8; m0++)
#pragma unroll
      for (int r = 0; r < 4; r++) {
        int f = m0 * 16 + lg * 4 + r;
        float wv = lv[m0][r] * inv;
        wsh[w][f * 16 + l4] = wv;
        wrow[f * 16 + l4] = wv;
      }
    float pv[16];
#pragma unroll
    for (int a = 0; a < 16; a++) pv[a] = 0.f;
#pragma unroll 4
    for (int f = 0; f < NF; f++) {
      float vv = b2f(Vbase[(long)f * DT + co + lane]);
      const float4* wp = (const float4*)&wsh[w][f * 16];
      float4 w0 = wp[0], w1 = wp[1], w2 = wp[2], w3 = wp[3];
      pv[0] += vv * w0.x;  pv[1] += vv * w0.y;  pv[2] += vv * w0.z;  pv[3] += vv * w0.w;
      pv[4] += vv * w1.x;  pv[5] += vv * w1.y;  pv[6] += vv * w1.z;  pv[7] += vv * w1.w;
      pv[8] += vv * w2.x;  pv[9] += vv * w2.y;  pv[10] += vv * w2.z; pv[11] += vv * w2.w;
      pv[12] += vv * w3.x; pv[13] += vv * w3.y; pv[14] += vv * w3.z; pv[15] += vv * w3.w;
    }
#pragma unroll
    for (int a = 0; a < 16; a++)
      attn_out[((long)tb * NA + a) * DT + co + lane] = f2b(pv[a]);
  }
}

extern "C" void kernel_launch(void* const* d_in, const int* in_sizes, int n_in,
                              void* d_out, int out_size, void* d_ws, size_t ws_size,
                              hipStream_t stream) {
  const float* q_embeds = (const float*)d_in[0];
  const float* ctx = (const float*)d_in[1];
  const int* mask = (const int*)d_in[2];
  const float* Wq = (const float*)d_in[3];
  const float* bq = (const float*)d_in[4];
  const float* Wk = (const float*)d_in[5];
  const float* bk = (const float*)d_in[6];
  const float* Wv = (const float*)d_in[7];
  const float* bv = (const float*)d_in[8];
  const float* Wo = (const float*)d_in[9];
  const float* bo = (const float*)d_in[10];

  float* out0 = (float*)d_out;                   // (t,a,b,d) f32
  float* wout = out0 + (long)NT * NA * NB * DT;  // (t,b,H,f,a) f32

  // workspace (bf16 as ushort) — exact round-1 footprint (606,076,928 B)
  const long W_ELEMS = 4L * 512 * 512;     // 1,048,576
  const long MQ = (long)NT * NB * NA;      // 32768
  const long MKV = (long)NT * NF * NB;     // 262144
  const long CHUNK_ROWS = MKV / 8;         // 32768 rows per ctx chunk
  unsigned short* Wb = (unsigned short*)d_ws;
  unsigned short* Qst = Wb + W_ELEMS;
  unsigned short* Kst = Qst + MQ * DT;
  unsigned short* Vst = Kst + MKV * DT;
  unsigned short* ctxb = Vst + MKV * DT;       // chunk buffer, 16.7M elems
  unsigned short* attnst = ctxb;               // alias: ctxb dead before attn runs
  size_t needed = (size_t)(W_ELEMS + MQ * DT + 2 * MKV * DT + CHUNK_ROWS * DT) * 2;
  if (ws_size < needed) return;

  cast_kernel<<<128, 256, 0, stream>>>(Wq, Wb);
  cast_kernel<<<128, 256, 0, stream>>>(Wk, Wb + 512 * 512);
  cast_kernel<<<128, 256, 0, stream>>>(Wv, Wb + 2 * 512 * 512);
  cast_kernel<<<128, 256, 0, stream>>>(Wo, Wb + 3 * 512 * 512);

  // Q projection (old path: f32 A, cvt in staging)
  gemm_q<<<dim3(MQ / 128, 4), 256, 0, stream>>>(q_embeds, Wb, bq, Qst);

  // K+V projection in 8 chunks: cast chunk -> bf16, then m97-structure GEMM
  for (int c = 0; c < 8; c++) {
    cast_kernel<<<(unsigned)(CHUNK_ROWS * DT / 2048), 256, 0, stream>>>(
        ctx + (long)c * CHUNK_ROWS * DT, ctxb);
    gemm_lds<MODE_KV, 3><<<(unsigned)(CHUNK_ROWS / 128 * 8), 256, 0, stream>>>(
        ctxb, Wb + 512 * 512, bk, bv, Kst, Vst, (long)c * CHUNK_ROWS);
  }

  attn_kernel<<<NT * NB, 256, 0, stream>>>(Kst, Vst, Qst, mask, wout, attnst);

  gemm_lds<MODE_O, 2><<<(unsigned)(MQ / 128 * 4), 256, 0, stream>>>(
      attnst, Wb + 3 * 512 * 512, bo, nullptr, out0, nullptr, 0);
}